// Round 12
// baseline (100.067 us; speedup 1.0000x reference)
//
#include <hip/hip_runtime.h>
#include <cstdint>

// HebbFF T=128,B=8,N=512,D=256,O=1. Gram-matrix reformulation:
//   z(t) = w_add@h_m(t) + b_add + sum_{s<t} W[t][s] u(s),  u = sigmoid(z)
//   W[t][s] = eta_a * lam_a^(t-1-s) * (h_m(s).h_m(t))
// R12: kill scratch spills in the mid kernels. R8-R11 staged streaming tiles
// through lambdas taking float4* -> local arrays demoted to SCRATCH (rule:
// pointer/runtime-indexed locals), VGPR_Count 52-56 vs ~140 needed; scratch
// is L2-side so FETCH/WRITE never showed it. Rewrite with NAMED registers
// via macros, by-value inline dot, launch_bounds(512,1). Split np_mid into
// np_base + np_gram for per-dispatch attribution.
// ws (floats): hp@0 (524288) | z0/u@524288 (524288) | W@1048576 (131072).

#define T_ 128
#define B_ 8
#define N_ 512
#define D_ 256
#define HP_OFF 0
#define Z0_OFF 524288
#define WS_OFF 1048576
#define WS_NEED ((size_t)(1048576 + 131072) * 4)
#define HOFF (T_ * B_ * N_)   // fallback layout
#define CH 16
#define NC (T_ / CH)

typedef float v2f __attribute__((ext_vector_type(2)));

__device__ __forceinline__ v2f v2(float s) { v2f r; r.x = s; r.y = s; return r; }
__device__ __forceinline__ v2f mk2(float a, float b) { v2f r; r.x = a; r.y = b; return r; }

__device__ __forceinline__ void load_lds16(const float* g, float* l) {
  __builtin_amdgcn_global_load_lds(
      (const __attribute__((address_space(1))) uint32_t*)(const void*)g,
      (__attribute__((address_space(3))) uint32_t*)(void*)l, 16, 0, 0);
}

#define DPP1(v, ctrl)                                                          \
  v += __int_as_float(                                                         \
      __builtin_amdgcn_update_dpp(0, __float_as_int(v), ctrl, 0xf, 0xf, true))

__device__ __forceinline__ float dpp_red(float v) {
  DPP1(v, 0x111); DPP1(v, 0x112); DPP1(v, 0x114); DPP1(v, 0x118);
  DPP1(v, 0x142); DPP1(v, 0x143);
  return v;
}
__device__ __forceinline__ v2f dpp_red2(v2f v) {
  float a = v.x, b = v.y;
  DPP1(a, 0x111); DPP1(b, 0x111); DPP1(a, 0x112); DPP1(b, 0x112);
  DPP1(a, 0x114); DPP1(b, 0x114); DPP1(a, 0x118); DPP1(b, 0x118);
  DPP1(a, 0x142); DPP1(b, 0x142); DPP1(a, 0x143); DPP1(b, 0x143);
  v.x = a; v.y = b;
  return v;
}
// 32-lane sum: lane31 = sum(0..31), lane63 = sum(32..63)
__device__ __forceinline__ float dpp_red1_32(float v) {
  DPP1(v, 0x111); DPP1(v, 0x112); DPP1(v, 0x114); DPP1(v, 0x118);
  DPP1(v, 0x142);
  return v;
}
__device__ __forceinline__ v2f dpp_red2_32(v2f v) {
  float a = v.x, b = v.y;
  DPP1(a, 0x111); DPP1(b, 0x111); DPP1(a, 0x112); DPP1(b, 0x112);
  DPP1(a, 0x114); DPP1(b, 0x114); DPP1(a, 0x118); DPP1(b, 0x118);
  DPP1(a, 0x142); DPP1(b, 0x142);
  v.x = a; v.y = b;
  return v;
}
__device__ __forceinline__ float dpp_wave_sum(float v) {
  v = dpp_red(v);
  return __int_as_float(__builtin_amdgcn_readlane(__float_as_int(v), 63));
}
__device__ __forceinline__ float sigmoid_f(float z) {
  return __builtin_amdgcn_rcpf(1.f + __expf(-z));
}
__device__ __forceinline__ float tanh_f(float z) {
  return 1.f - 2.f * __builtin_amdgcn_rcpf(1.f + __expf(2.f * z));
}

// 16-term paired dot: pairs (te,to) of 8 consecutive h float4s vs 4 w float4s
__device__ __forceinline__ v2f dot8p(float4 w0, float4 w1, float4 w2, float4 w3,
                                     float4 h0, float4 h1, float4 h2, float4 h3,
                                     float4 h4, float4 h5, float4 h6, float4 h7) {
  v2f a = mk2(h0.x, h0.y) * v2(w0.x);
  a = __builtin_elementwise_fma(mk2(h0.z, h0.w), v2(w0.y), a);
  a = __builtin_elementwise_fma(mk2(h1.x, h1.y), v2(w0.z), a);
  a = __builtin_elementwise_fma(mk2(h1.z, h1.w), v2(w0.w), a);
  a = __builtin_elementwise_fma(mk2(h2.x, h2.y), v2(w1.x), a);
  a = __builtin_elementwise_fma(mk2(h2.z, h2.w), v2(w1.y), a);
  a = __builtin_elementwise_fma(mk2(h3.x, h3.y), v2(w1.z), a);
  a = __builtin_elementwise_fma(mk2(h3.z, h3.w), v2(w1.w), a);
  a = __builtin_elementwise_fma(mk2(h4.x, h4.y), v2(w2.x), a);
  a = __builtin_elementwise_fma(mk2(h4.z, h4.w), v2(w2.y), a);
  a = __builtin_elementwise_fma(mk2(h5.x, h5.y), v2(w2.z), a);
  a = __builtin_elementwise_fma(mk2(h5.z, h5.w), v2(w2.w), a);
  a = __builtin_elementwise_fma(mk2(h6.x, h6.y), v2(w3.x), a);
  a = __builtin_elementwise_fma(mk2(h6.z, h6.w), v2(w3.y), a);
  a = __builtin_elementwise_fma(mk2(h7.x, h7.y), v2(w3.z), a);
  a = __builtin_elementwise_fma(mk2(h7.z, h7.w), v2(w3.w), a);
  return a;
}

// ---------------- np_part1: h_mult / A_mult chain (32-lane split) ----------
__global__ void __launch_bounds__(512, 1)
np_part1(const float* __restrict__ x, const float* __restrict__ w_mult,
         const float* __restrict__ b_mult, const float* __restrict__ p_lm,
         const float* __restrict__ p_em, float* __restrict__ ws) {
  const int g = blockIdx.x & 7, sub = blockIdx.x >> 3;
  const int wave = threadIdx.x >> 6, lane = threadIdx.x & 63;
  const int l31 = lane & 31, half = lane >> 5;
  const int n0 = (sub * 8 + wave) * 2;
  const int n = n0 + half;

  __shared__ float xs[T_][D_];  // 128 KB: ALL x rows for batch g
#pragma unroll
  for (int i = 0; i < 16; ++i) {
    const int r = wave * 16 + i;
    load_lds16(&x[(r * B_ + g) * D_ + 4 * lane], &xs[r][0]);
  }

  const float lam = sigmoid_f(p_lm[0]);
  const float eta = p_em[0];
  const v2f lam2 = v2(lam), klam2 = v2(1.f - lam);

  v2f wm[4], Bm[4];
#pragma unroll
  for (int c = 0; c < 4; ++c) {
    wm[c] = *(const v2f*)&w_mult[n * D_ + 64 * c + 2 * l31];
    Bm[c] = v2(1.f);
  }
  const float bm = b_mult[n];
  __syncthreads();  // x staged (drains vmcnt)

  float* hp = ws + HP_OFF;
  v2f xv[4][4];  // 4-slot ring, constant-indexed in unrolled loop
#define LDX(slot, t)                                                           \
  {                                                                            \
    _Pragma("unroll") for (int c = 0; c < 4; ++c)                              \
        xv[slot][c] = *(const v2f*)&xs[t][64 * c + 2 * l31];                   \
  }
  LDX(0, 0) LDX(1, 1) LDX(2, 2)

  float ph = 0.f;
  for (int t4 = 0; t4 < T_; t4 += 4) {
#pragma unroll
    for (int j = 0; j < 4; ++j) {
      const int t = t4 + j;
      if (t + 3 < T_) LDX((j + 3) & 3, t + 3)
      v2f wx = wm[0] * xv[j][0];
      v2f a = wx * Bm[0];
#pragma unroll
      for (int c = 1; c < 4; ++c) {
        wx = wm[c] * xv[j][c];
        a = __builtin_elementwise_fma(wx, Bm[c], a);
      }
      float s = dpp_red1_32(a.x + a.y);
      const float zr0 =
          __int_as_float(__builtin_amdgcn_readlane(__float_as_int(s), 31));
      const float zr1 =
          __int_as_float(__builtin_amdgcn_readlane(__float_as_int(s), 63));
      const float zz = (half ? zr1 : zr0) + bm;
      const float hm = tanh_f(zz);
      const v2f c2 = v2(eta * hm);
#pragma unroll
      for (int c = 0; c < 4; ++c) {
        v2f inner = __builtin_elementwise_fma(c2, xv[j][c], klam2);
        Bm[c] = __builtin_elementwise_fma(lam2, Bm[c], inner);
      }
      if (j & 1) {
        if (l31 == 31)
          *(v2f*)(hp + (size_t)((t >> 1) * B_ + g) * (N_ * 2) + n * 2) =
              mk2(ph, hm);
      } else {
        ph = hm;
      }
    }
  }
#undef LDX
}

// ---------------- np_base: z0 = h @ w_add^T (named-register pipeline) ------
// 256 blocks = 8 n-groups x 32 pr-groups (16 pr). No LDS, no lambdas.
__global__ void __launch_bounds__(512, 1)
np_base(const float* __restrict__ w_add, float* __restrict__ ws) {
  const int ng = blockIdx.x >> 5, pg = blockIdx.x & 31;
  const int wave = threadIdx.x >> 6, lane = threadIdx.x & 63;
  const int l31 = lane & 31, half = lane >> 5;
  const int nb = ng * 64 + wave * 8 + half * 4;
  const float* hp = ws + HP_OFF;
  float* z0 = ws + Z0_OFF;

  // w regs: wreg[i][jj] = w_add[nb+i][4*l31 + 128*jj .. +3] (const-indexed)
  float4 wreg[4][4];
#pragma unroll
  for (int i = 0; i < 4; ++i) {
    const float* wr = w_add + (size_t)(nb + i) * N_ + 4 * l31;
#pragma unroll
    for (int jj = 0; jj < 4; ++jj)
      wreg[i][jj] = *(const float4*)&wr[128 * jj];
  }

  const float* hbase = hp + (size_t)pg * 16 * 1024 + 8 * l31;

#define LDH(h0, h1, h2, h3, h4, h5, h6, h7, it)                                \
  do {                                                                         \
    const float* hr_ = hbase + (size_t)(it) * 1024;                            \
    h0 = *(const float4*)&hr_[0];                                              \
    h1 = *(const float4*)&hr_[4];                                              \
    h2 = *(const float4*)&hr_[256];                                            \
    h3 = *(const float4*)&hr_[260];                                            \
    h4 = *(const float4*)&hr_[512];                                            \
    h5 = *(const float4*)&hr_[516];                                            \
    h6 = *(const float4*)&hr_[768];                                            \
    h7 = *(const float4*)&hr_[772];                                            \
  } while (0)

#define CMPB(h0, h1, h2, h3, h4, h5, h6, h7, it)                               \
  do {                                                                         \
    const int pr_ = pg * 16 + (it);                                            \
    const int rowe_ = 16 * (pr_ >> 3) + (pr_ & 7);                             \
    v2f a0_ = dot8p(wreg[0][0], wreg[0][1], wreg[0][2], wreg[0][3],            \
                    h0, h1, h2, h3, h4, h5, h6, h7);                           \
    v2f a1_ = dot8p(wreg[1][0], wreg[1][1], wreg[1][2], wreg[1][3],            \
                    h0, h1, h2, h3, h4, h5, h6, h7);                           \
    v2f a2_ = dot8p(wreg[2][0], wreg[2][1], wreg[2][2], wreg[2][3],            \
                    h0, h1, h2, h3, h4, h5, h6, h7);                           \
    v2f a3_ = dot8p(wreg[3][0], wreg[3][1], wreg[3][2], wreg[3][3],            \
                    h0, h1, h2, h3, h4, h5, h6, h7);                           \
    a0_ = dpp_red2_32(a0_);                                                    \
    a1_ = dpp_red2_32(a1_);                                                    \
    a2_ = dpp_red2_32(a2_);                                                    \
    a3_ = dpp_red2_32(a3_);                                                    \
    if (l31 == 31) {                                                           \
      *(float4*)&z0[rowe_ * N_ + nb] =                                         \
          make_float4(a0_.x, a1_.x, a2_.x, a3_.x);                             \
      *(float4*)&z0[(rowe_ + 8) * N_ + nb] =                                   \
          make_float4(a0_.y, a1_.y, a2_.y, a3_.y);                             \
    }                                                                          \
  } while (0)

  float4 A0, A1, A2, A3, A4, A5, A6, A7;
  float4 B0, B1, B2, B3, B4, B5, B6, B7;
  LDH(A0, A1, A2, A3, A4, A5, A6, A7, 0);
  for (int it = 0; it < 16; it += 2) {
    LDH(B0, B1, B2, B3, B4, B5, B6, B7, it + 1);
    CMPB(A0, A1, A2, A3, A4, A5, A6, A7, it);
    if (it + 2 < 16) LDH(A0, A1, A2, A3, A4, A5, A6, A7, it + 2);
    CMPB(B0, B1, B2, B3, B4, B5, B6, B7, it + 1);
  }
#undef LDH
#undef CMPB
}

// ---------------- np_gram: W[b][t][s] (named-register pipeline) ------------
// 64 blocks: (b, qq); wave halves handle q=qq and q=15-qq (balanced).
__global__ void __launch_bounds__(512, 1)
np_gram(const float* __restrict__ p_la, const float* __restrict__ p_ea,
        float* __restrict__ ws) {
  __shared__ float hl[8192];  // 2 x 16 KB halves
  const int wave = threadIdx.x >> 6, lane = threadIdx.x & 63;
  const float* hp = ws + HP_OFF;
  float* Wsc = ws + WS_OFF;
  const int b = blockIdx.x & 7, qq = blockIdx.x >> 3;
  const int hlf = wave >> 2, w4 = wave & 3;
  const int q = hlf ? (15 - qq) : qq;
  float* hb = hl + hlf * 4096;
  const float lam = sigmoid_f(p_la[0]);
  const float eta = p_ea[0];
#pragma unroll
  for (int i = 0; i < 4; ++i)
    load_lds16(&hp[((q * 4 + w4) * 8 + b) * 1024 + i * 256 + 4 * lane],
               &hb[w4 * 1024 + i * 256]);
  __syncthreads();
  v2f hv[4][8];  // constant-indexed
#pragma unroll
  for (int i = 0; i < 4; ++i)
#pragma unroll
    for (int j = 0; j < 8; ++j)
      hv[i][j] = ((const v2f*)hb)[i * 512 + lane + 64 * j];

  const float l2lam = __log2f(lam);
  const int tlim = q * 8 + 7;

#define LDG(p0, p1, p2, p3, p4, p5, p6, p7, tp)                                \
  do {                                                                         \
    const float* hr_ = hp + (((tp) >> 1) * 8 + b) * 1024 + ((tp) & 1);         \
    p0 = hr_[2 * lane];                                                        \
    p1 = hr_[2 * lane + 128];                                                  \
    p2 = hr_[2 * lane + 256];                                                  \
    p3 = hr_[2 * lane + 384];                                                  \
    p4 = hr_[2 * lane + 512];                                                  \
    p5 = hr_[2 * lane + 640];                                                  \
    p6 = hr_[2 * lane + 768];                                                  \
    p7 = hr_[2 * lane + 896];                                                  \
  } while (0)

#define CMPG(p0, p1, p2, p3, p4, p5, p6, p7, tp)                               \
  do {                                                                         \
    _Pragma("unroll") for (int i_ = 0; i_ < 4; ++i_) {                         \
      v2f a_ = hv[i_][0] * v2(p0);                                             \
      a_ = __builtin_elementwise_fma(hv[i_][1], v2(p1), a_);                   \
      a_ = __builtin_elementwise_fma(hv[i_][2], v2(p2), a_);                   \
      a_ = __builtin_elementwise_fma(hv[i_][3], v2(p3), a_);                   \
      a_ = __builtin_elementwise_fma(hv[i_][4], v2(p4), a_);                   \
      a_ = __builtin_elementwise_fma(hv[i_][5], v2(p5), a_);                   \
      a_ = __builtin_elementwise_fma(hv[i_][6], v2(p6), a_);                   \
      a_ = __builtin_elementwise_fma(hv[i_][7], v2(p7), a_);                   \
      a_ = dpp_red2(a_);                                                       \
      if (lane == 63) {                                                        \
        const int te_ = q * 8 + 2 * i_;                                        \
        if ((tp) < te_)                                                        \
          Wsc[(b * T_ + te_) * T_ + (tp)] =                                    \
              eta * exp2f(l2lam * (float)(te_ - 1 - (tp))) * a_.x;             \
        if ((tp) < te_ + 1)                                                    \
          Wsc[(b * T_ + te_ + 1) * T_ + (tp)] =                                \
              eta * exp2f(l2lam * (float)(te_ - (tp))) * a_.y;                 \
      }                                                                        \
    }                                                                          \
  } while (0)

  float ra0, ra1, ra2, ra3, ra4, ra5, ra6, ra7;
  float rb0, rb1, rb2, rb3, rb4, rb5, rb6, rb7;
  if (w4 < tlim) LDG(ra0, ra1, ra2, ra3, ra4, ra5, ra6, ra7, w4);
  for (int tp = w4; tp < tlim; tp += 4) {
    if (tp + 4 < tlim) LDG(rb0, rb1, rb2, rb3, rb4, rb5, rb6, rb7, tp + 4);
    CMPG(ra0, ra1, ra2, ra3, ra4, ra5, ra6, ra7, tp);
    ra0 = rb0; ra1 = rb1; ra2 = rb2; ra3 = rb3;
    ra4 = rb4; ra5 = rb5; ra6 = rb6; ra7 = rb7;
  }
#undef LDG
#undef CMPG
}

// ---------------- np_scan: sequential sigmoid scan ----------------
__global__ void __launch_bounds__(512, 1)
np_scan(const float* __restrict__ b_add, float* __restrict__ ws) {
  __shared__ float Wl[T_][T_];   // 64 KB
  __shared__ float ul[T_][64];   // 32 KB
  __shared__ float zx[16][64];   // 4 KB
  const int b = blockIdx.x >> 3, nc = blockIdx.x & 7;
  const int wave = threadIdx.x >> 6, lane = threadIdx.x & 63;
  float* z0 = ws + Z0_OFF;
  const float* Wb = ws + WS_OFF + b * T_ * T_;

#pragma unroll
  for (int i = 0; i < 8; ++i) {
    const int r2 = wave * 16 + i * 2;
    load_lds16(&Wb[r2 * T_ + 4 * lane], &Wl[r2][0]);
  }

  const int ta = 2 * wave, tb2 = 2 * wave + 1;
  const int ncol = nc * 64 + lane;
  const float ban = b_add[ncol];

  float za = z0[(ta * B_ + b) * N_ + ncol] + ban;
  float zb = z0[(tb2 * B_ + b) * N_ + ncol] + ban;
  __syncthreads();  // W staged

  for (int j = 0; j < 8; ++j) {
    const int t0 = j * 16;
    float zna = 0.f, znb = 0.f;
    if (j < 7) {
      zna = z0[((t0 + 16 + ta) * B_ + b) * N_ + ncol] + ban;
      znb = z0[((t0 + 16 + tb2) * B_ + b) * N_ + ncol] + ban;
    }
    float ha0 = 0.f, ha1 = 0.f, hb0 = 0.f, hb1 = 0.f;
#pragma unroll 2
    for (int s4 = 0; s4 < t0; s4 += 4) {
      const float4 wa = *(const float4*)&Wl[t0 + ta][s4];
      const float4 wb = *(const float4*)&Wl[t0 + tb2][s4];
      const float u0 = ul[s4 + 0][lane], u1 = ul[s4 + 1][lane];
      const float u2 = ul[s4 + 2][lane], u3 = ul[s4 + 3][lane];
      ha0 = __builtin_fmaf(wa.x, u0, ha0);
      ha1 = __builtin_fmaf(wa.y, u1, ha1);
      ha0 = __builtin_fmaf(wa.z, u2, ha0);
      ha1 = __builtin_fmaf(wa.w, u3, ha1);
      hb0 = __builtin_fmaf(wb.x, u0, hb0);
      hb1 = __builtin_fmaf(wb.y, u1, hb1);
      hb0 = __builtin_fmaf(wb.z, u2, hb0);
      hb1 = __builtin_fmaf(wb.w, u3, hb1);
    }
    zx[ta][lane] = za + (ha0 + ha1);
    zx[tb2][lane] = zb + (hb0 + hb1);
    __syncthreads();
    if (wave == 0) {
      float z[16], uv[16];
#pragma unroll
      for (int i = 0; i < 16; ++i) z[i] = zx[i][lane];
#pragma unroll
      for (int i = 0; i < 16; ++i) {
        const float u = sigmoid_f(z[i]);
        uv[i] = u;
        z0[((t0 + i) * B_ + b) * N_ + ncol] = u;  // in-place u
#pragma unroll
        for (int tt = i + 1; tt < 16; ++tt)
          z[tt] = __builtin_fmaf(u, Wl[t0 + tt][t0 + i], z[tt]);
      }
#pragma unroll
      for (int i = 0; i < 16; ++i) ul[t0 + i][lane] = uv[i];
    }
    __syncthreads();
    za = zna;
    zb = znb;
  }
}

// ---------------- np_final ----------------
__global__ void __launch_bounds__(512)
np_final(const float* __restrict__ ws, const float* __restrict__ w_final,
         const float* __restrict__ b_final, float* __restrict__ out) {
  const int wave = threadIdx.x >> 6, lane = threadIdx.x & 63;
  const int tb = blockIdx.x * 8 + wave;
  const float* u = ws + Z0_OFF + tb * N_ + lane * 8;
  const float4 a = *(const float4*)u, c = *(const float4*)(u + 4);
  const float4 wa = *(const float4*)&w_final[lane * 8];
  const float4 wc = *(const float4*)&w_final[lane * 8 + 4];
  float d = a.x * wa.x + a.y * wa.y + a.z * wa.z + a.w * wa.w +
            c.x * wc.x + c.y * wc.y + c.z * wc.z + c.w * wc.w;
  d = dpp_wave_sum(d);
  if (lane == 0) out[tb] = sigmoid_f(d + b_final[0]);
}

// ================= fallback path (R5) =================

__global__ void __launch_bounds__(512, 2)
fb_part1(const float* __restrict__ x, const float* __restrict__ w_mult,
         const float* __restrict__ b_mult, const float* __restrict__ p_lm,
         const float* __restrict__ p_em, float* __restrict__ ws) {
  const int g = blockIdx.x & 7, sub = blockIdx.x >> 3;
  const int wave = threadIdx.x >> 6, lane = threadIdx.x & 63;
  const int n0 = (sub * 8 + wave) * 2;
  __shared__ float xs[2][CH][D_];
  const float lam = sigmoid_f(p_lm[0]);
  const float eta = p_em[0];
  const v2f lam2 = v2(lam), klam2 = v2(1.f - lam);
  v2f wm[2][2], Bm[2][2];
  float bm[2];
#pragma unroll
  for (int r = 0; r < 2; ++r) {
    bm[r] = b_mult[n0 + r];
#pragma unroll
    for (int c = 0; c < 2; ++c) {
      wm[r][c] = *(const v2f*)&w_mult[(n0 + r) * D_ + c * 128 + 2 * lane];
      Bm[r][c] = v2(1.f);
    }
  }
  auto issue_stage = [&](int c) {
#pragma unroll
    for (int k = 0; k < 2; ++k) {
      const int row = k * 8 + wave;
      load_lds16(&x[((c * CH + row) * B_ + g) * D_ + 4 * lane],
                 &xs[c & 1][row][0]);
    }
  };
  issue_stage(0);
  __syncthreads();
  v2f xv[2][2];
  auto ldx = [&](int buf, int cb, int tl) {
    xv[buf][0] = *(const v2f*)&xs[cb][tl][2 * lane];
    xv[buf][1] = *(const v2f*)&xs[cb][tl][128 + 2 * lane];
  };
  for (int c = 0; c < NC; ++c) {
    if (c + 1 < NC) issue_stage(c + 1);
    const int cb = c & 1;
    ldx(0, cb, 0);
#pragma unroll
    for (int tl = 0; tl < CH; ++tl) {
      const int buf = tl & 1;
      if (tl + 1 < CH) ldx(buf ^ 1, cb, tl + 1);
      float hmv[2];
#pragma unroll
      for (int r = 0; r < 2; ++r) {
        v2f a = wm[r][0] * xv[buf][0] * Bm[r][0];
        a = __builtin_elementwise_fma(wm[r][1] * xv[buf][1], Bm[r][1], a);
        const float z = dpp_wave_sum(a.x + a.y) + bm[r];
        const float hm = tanh_f(z);
        hmv[r] = hm;
        const v2f c2 = v2(eta * hm);
#pragma unroll
        for (int cc = 0; cc < 2; ++cc) {
          v2f inner = __builtin_elementwise_fma(c2, xv[buf][cc], klam2);
          Bm[r][cc] = __builtin_elementwise_fma(lam2, Bm[r][cc], inner);
        }
      }
      if (lane == 0) {
        v2f hv2;
        hv2.x = hmv[0];
        hv2.y = hmv[1];
        *(v2f*)(ws + ((c * CH + tl) * B_ + g) * N_ + n0) = hv2;
      }
    }
    __syncthreads();
  }
}

__global__ void __launch_bounds__(512, 2)
fb_part2(const float* __restrict__ w_add, const float* __restrict__ b_add,
         const float* __restrict__ w_final, const float* __restrict__ p_la,
         const float* __restrict__ p_ea, float* __restrict__ ws) {
  const int g = blockIdx.x & 7, sub = blockIdx.x >> 3;
  const int wave = threadIdx.x >> 6, lane = threadIdx.x & 63;
  const int n0 = (sub * 8 + wave) * 2;
  __shared__ float hs[2][CH][N_];
  const float lam = sigmoid_f(p_la[0]);
  const float eta = p_ea[0];
  const v2f lam2 = v2(lam);
  const float klam = 1.f - lam;
  v2f Sa[2][4], wb[2][4];
  float ba[2], wf[2];
#pragma unroll
  for (int r = 0; r < 2; ++r) {
    ba[r] = b_add[n0 + r];
    wf[r] = w_final[n0 + r];
#pragma unroll
    for (int c = 0; c < 4; ++c) {
      const v2f wa = *(const v2f*)&w_add[(n0 + r) * N_ + c * 128 + 2 * lane];
      Sa[r][c] = wa;
      wb[r][c] = wa * klam;
    }
  }
  const float* hsrc = ws;
  float* part = ws + HOFF;
  auto issue_stage = [&](int c) {
#pragma unroll
    for (int k = 0; k < 2; ++k) {
      const int row = k * 8 + wave;
#pragma unroll
      for (int jj = 0; jj < 2; ++jj)
        load_lds16(&hsrc[((c * CH + row) * B_ + g) * N_ + jj * 256 + 4 * lane],
                   &hs[c & 1][row][jj * 256]);
    }
  };
  issue_stage(0);
  __syncthreads();
  v2f hv[2][4];
  auto ldh = [&](int buf, int cb, int tl) {
#pragma unroll
    for (int cc = 0; cc < 4; ++cc)
      hv[buf][cc] = *(const v2f*)&hs[cb][tl][cc * 128 + 2 * lane];
  };
  for (int c = 0; c < NC; ++c) {
    if (c + 1 < NC) issue_stage(c + 1);
    const int cb = c & 1;
    ldh(0, cb, 0);
#pragma unroll
    for (int tl = 0; tl < CH; ++tl) {
      const int buf = tl & 1;
      if (tl + 1 < CH) ldh(buf ^ 1, cb, tl + 1);
      float py = 0.f;
#pragma unroll
      for (int r = 0; r < 2; ++r) {
        v2f a0 = Sa[r][0] * hv[buf][0];
        v2f a1 = Sa[r][1] * hv[buf][1];
        a0 = __builtin_elementwise_fma(Sa[r][2], hv[buf][2], a0);
        a1 = __builtin_elementwise_fma(Sa[r][3], hv[buf][3], a1);
        const v2f a = a0 + a1;
        const float z = dpp_wave_sum(a.x + a.y) + ba[r];
        const float ha = sigmoid_f(z);
        const v2f c2 = v2(eta * ha);
#pragma unroll
        for (int cc = 0; cc < 4; ++cc) {
          v2f inner = __builtin_elementwise_fma(c2, hv[buf][cc], wb[r][cc]);
          Sa[r][cc] = __builtin_elementwise_fma(lam2, Sa[r][cc], inner);
        }
        py = __builtin_fmaf(wf[r], ha, py);
      }
      if (lane == 0)
        part[((c * CH + tl) * B_ + g) * 256 + sub * 8 + wave] = py;
    }
    __syncthreads();
  }
}

__global__ void __launch_bounds__(512)
fb_final(const float* __restrict__ ws, const float* __restrict__ b_final,
         float* __restrict__ out) {
  const int wave = threadIdx.x >> 6, lane = threadIdx.x & 63;
  const int tb = blockIdx.x * 8 + wave;
  const float4 v = *(const float4*)(ws + HOFF + tb * 256 + lane * 4);
  const float s = dpp_wave_sum((v.x + v.y) + (v.z + v.w));
  if (lane == 0) out[tb] = sigmoid_f(s + b_final[0]);
}

// ================= launch =================

extern "C" void kernel_launch(void* const* d_in, const int* in_sizes, int n_in,
                              void* d_out, int out_size, void* d_ws,
                              size_t ws_size, hipStream_t stream) {
  const float* x       = (const float*)d_in[0];
  const float* w_mult  = (const float*)d_in[1];
  const float* b_mult  = (const float*)d_in[2];
  const float* w_add   = (const float*)d_in[3];
  const float* b_add   = (const float*)d_in[4];
  const float* w_final = (const float*)d_in[5];
  const float* b_final = (const float*)d_in[6];
  const float* p_lm    = (const float*)d_in[7];
  const float* p_la    = (const float*)d_in[8];
  const float* p_em    = (const float*)d_in[9];
  const float* p_ea    = (const float*)d_in[10];
  float* out = (float*)d_out;
  float* ws  = (float*)d_ws;

  if (ws_size >= WS_NEED) {
    hipLaunchKernelGGL(np_part1, dim3(256), dim3(512), 0, stream,
                       x, w_mult, b_mult, p_lm, p_em, ws);
    hipLaunchKernelGGL(np_base, dim3(256), dim3(512), 0, stream, w_add, ws);
    hipLaunchKernelGGL(np_gram, dim3(64), dim3(512), 0, stream,
                       p_la, p_ea, ws);
    hipLaunchKernelGGL(np_scan, dim3(64), dim3(512), 0, stream, b_add, ws);
    hipLaunchKernelGGL(np_final, dim3(128), dim3(512), 0, stream,
                       ws, w_final, b_final, out);
  } else {
    hipLaunchKernelGGL(fb_part1, dim3(256), dim3(512), 0, stream,
                       x, w_mult, b_mult, p_lm, p_em, ws);
    hipLaunchKernelGGL(fb_part2, dim3(256), dim3(512), 0, stream,
                       w_add, b_add, w_final, p_la, p_ea, ws);
    hipLaunchKernelGGL(fb_final, dim3(128), dim3(512), 0, stream,
                       ws, b_final, out);
  }
}

// Round 13
// 80.044 us; speedup vs baseline: 1.2501x; 1.2501x over previous
//
#include <hip/hip_runtime.h>
#include <cstdint>

// HebbFF T=128,B=8,N=512,D=256,O=1. Gram-matrix reformulation:
//   z(t) = w_add@h_m(t) + b_add + sum_{s<t} W[t][s] u(s),  u = sigmoid(z)
//   W[t][s] = eta_a * lam_a^(t-1-s) * (h_m(s).h_m(t))
// R13:
//   np_mid: gram (blocks 0..63, balanced q-pairs) + base (64..319, 16-pr
//     M-tile) RE-MERGED for concurrency, with R12's named-register bodies
//     (no lambdas/pointer-staged locals -> no scratch demotion).
//   np_scan: RIGHT-LOOKING rewrite: each wave holds z[2 rows x 8 tiles] in
//     registers; after each tile's triangle, scatter-forward that tile's u
//     into all future z. u-history LDS traffic O(T^2) -> O(T); ul 32KB->4KB.
// ws (floats): hp@0 (524288) | z0/u@524288 (524288) | W@1048576 (131072).

#define T_ 128
#define B_ 8
#define N_ 512
#define D_ 256
#define HP_OFF 0
#define Z0_OFF 524288
#define WS_OFF 1048576
#define WS_NEED ((size_t)(1048576 + 131072) * 4)
#define HOFF (T_ * B_ * N_)   // fallback layout
#define CH 16
#define NC (T_ / CH)

typedef float v2f __attribute__((ext_vector_type(2)));

__device__ __forceinline__ v2f v2(float s) { v2f r; r.x = s; r.y = s; return r; }
__device__ __forceinline__ v2f mk2(float a, float b) { v2f r; r.x = a; r.y = b; return r; }

__device__ __forceinline__ void load_lds16(const float* g, float* l) {
  __builtin_amdgcn_global_load_lds(
      (const __attribute__((address_space(1))) uint32_t*)(const void*)g,
      (__attribute__((address_space(3))) uint32_t*)(void*)l, 16, 0, 0);
}

#define DPP1(v, ctrl)                                                          \
  v += __int_as_float(                                                         \
      __builtin_amdgcn_update_dpp(0, __float_as_int(v), ctrl, 0xf, 0xf, true))

__device__ __forceinline__ float dpp_red(float v) {
  DPP1(v, 0x111); DPP1(v, 0x112); DPP1(v, 0x114); DPP1(v, 0x118);
  DPP1(v, 0x142); DPP1(v, 0x143);
  return v;
}
__device__ __forceinline__ v2f dpp_red2(v2f v) {
  float a = v.x, b = v.y;
  DPP1(a, 0x111); DPP1(b, 0x111); DPP1(a, 0x112); DPP1(b, 0x112);
  DPP1(a, 0x114); DPP1(b, 0x114); DPP1(a, 0x118); DPP1(b, 0x118);
  DPP1(a, 0x142); DPP1(b, 0x142); DPP1(a, 0x143); DPP1(b, 0x143);
  v.x = a; v.y = b;
  return v;
}
// 32-lane sum: lane31 = sum(0..31), lane63 = sum(32..63)
__device__ __forceinline__ float dpp_red1_32(float v) {
  DPP1(v, 0x111); DPP1(v, 0x112); DPP1(v, 0x114); DPP1(v, 0x118);
  DPP1(v, 0x142);
  return v;
}
__device__ __forceinline__ v2f dpp_red2_32(v2f v) {
  float a = v.x, b = v.y;
  DPP1(a, 0x111); DPP1(b, 0x111); DPP1(a, 0x112); DPP1(b, 0x112);
  DPP1(a, 0x114); DPP1(b, 0x114); DPP1(a, 0x118); DPP1(b, 0x118);
  DPP1(a, 0x142); DPP1(b, 0x142);
  v.x = a; v.y = b;
  return v;
}
__device__ __forceinline__ float dpp_wave_sum(float v) {
  v = dpp_red(v);
  return __int_as_float(__builtin_amdgcn_readlane(__float_as_int(v), 63));
}
__device__ __forceinline__ float sigmoid_f(float z) {
  return __builtin_amdgcn_rcpf(1.f + __expf(-z));
}
__device__ __forceinline__ float tanh_f(float z) {
  return 1.f - 2.f * __builtin_amdgcn_rcpf(1.f + __expf(2.f * z));
}

// 16-term paired dot: pairs (te,to) of 8 consecutive h float4s vs 4 w float4s
__device__ __forceinline__ v2f dot8p(float4 w0, float4 w1, float4 w2, float4 w3,
                                     float4 h0, float4 h1, float4 h2, float4 h3,
                                     float4 h4, float4 h5, float4 h6, float4 h7) {
  v2f a = mk2(h0.x, h0.y) * v2(w0.x);
  a = __builtin_elementwise_fma(mk2(h0.z, h0.w), v2(w0.y), a);
  a = __builtin_elementwise_fma(mk2(h1.x, h1.y), v2(w0.z), a);
  a = __builtin_elementwise_fma(mk2(h1.z, h1.w), v2(w0.w), a);
  a = __builtin_elementwise_fma(mk2(h2.x, h2.y), v2(w1.x), a);
  a = __builtin_elementwise_fma(mk2(h2.z, h2.w), v2(w1.y), a);
  a = __builtin_elementwise_fma(mk2(h3.x, h3.y), v2(w1.z), a);
  a = __builtin_elementwise_fma(mk2(h3.z, h3.w), v2(w1.w), a);
  a = __builtin_elementwise_fma(mk2(h4.x, h4.y), v2(w2.x), a);
  a = __builtin_elementwise_fma(mk2(h4.z, h4.w), v2(w2.y), a);
  a = __builtin_elementwise_fma(mk2(h5.x, h5.y), v2(w2.z), a);
  a = __builtin_elementwise_fma(mk2(h5.z, h5.w), v2(w2.w), a);
  a = __builtin_elementwise_fma(mk2(h6.x, h6.y), v2(w3.x), a);
  a = __builtin_elementwise_fma(mk2(h6.z, h6.w), v2(w3.y), a);
  a = __builtin_elementwise_fma(mk2(h7.x, h7.y), v2(w3.z), a);
  a = __builtin_elementwise_fma(mk2(h7.z, h7.w), v2(w3.w), a);
  return a;
}

// ---------------- np_part1: h_mult / A_mult chain (32-lane split) ----------
__global__ void __launch_bounds__(512, 1)
np_part1(const float* __restrict__ x, const float* __restrict__ w_mult,
         const float* __restrict__ b_mult, const float* __restrict__ p_lm,
         const float* __restrict__ p_em, float* __restrict__ ws) {
  const int g = blockIdx.x & 7, sub = blockIdx.x >> 3;
  const int wave = threadIdx.x >> 6, lane = threadIdx.x & 63;
  const int l31 = lane & 31, half = lane >> 5;
  const int n0 = (sub * 8 + wave) * 2;
  const int n = n0 + half;

  __shared__ float xs[T_][D_];  // 128 KB: ALL x rows for batch g
#pragma unroll
  for (int i = 0; i < 16; ++i) {
    const int r = wave * 16 + i;
    load_lds16(&x[(r * B_ + g) * D_ + 4 * lane], &xs[r][0]);
  }

  const float lam = sigmoid_f(p_lm[0]);
  const float eta = p_em[0];
  const v2f lam2 = v2(lam), klam2 = v2(1.f - lam);

  v2f wm[4], Bm[4];
#pragma unroll
  for (int c = 0; c < 4; ++c) {
    wm[c] = *(const v2f*)&w_mult[n * D_ + 64 * c + 2 * l31];
    Bm[c] = v2(1.f);
  }
  const float bm = b_mult[n];
  __syncthreads();  // x staged (drains vmcnt)

  float* hp = ws + HP_OFF;
  v2f xv[4][4];  // 4-slot ring, constant-indexed in unrolled loop
#define LDX(slot, t)                                                           \
  {                                                                            \
    _Pragma("unroll") for (int c = 0; c < 4; ++c)                              \
        xv[slot][c] = *(const v2f*)&xs[t][64 * c + 2 * l31];                   \
  }
  LDX(0, 0) LDX(1, 1) LDX(2, 2)

  float ph = 0.f;
  for (int t4 = 0; t4 < T_; t4 += 4) {
#pragma unroll
    for (int j = 0; j < 4; ++j) {
      const int t = t4 + j;
      if (t + 3 < T_) LDX((j + 3) & 3, t + 3)
      v2f wx = wm[0] * xv[j][0];
      v2f a = wx * Bm[0];
#pragma unroll
      for (int c = 1; c < 4; ++c) {
        wx = wm[c] * xv[j][c];
        a = __builtin_elementwise_fma(wx, Bm[c], a);
      }
      float s = dpp_red1_32(a.x + a.y);
      const float zr0 =
          __int_as_float(__builtin_amdgcn_readlane(__float_as_int(s), 31));
      const float zr1 =
          __int_as_float(__builtin_amdgcn_readlane(__float_as_int(s), 63));
      const float zz = (half ? zr1 : zr0) + bm;
      const float hm = tanh_f(zz);
      const v2f c2 = v2(eta * hm);
#pragma unroll
      for (int c = 0; c < 4; ++c) {
        v2f inner = __builtin_elementwise_fma(c2, xv[j][c], klam2);
        Bm[c] = __builtin_elementwise_fma(lam2, Bm[c], inner);
      }
      if (j & 1) {
        if (l31 == 31)
          *(v2f*)(hp + (size_t)((t >> 1) * B_ + g) * (N_ * 2) + n * 2) =
              mk2(ph, hm);
      } else {
        ph = hm;
      }
    }
  }
#undef LDX
}

// ---------------- np_mid: gram (0..63) + base (64..319), concurrent --------
__global__ void __launch_bounds__(512, 1)
np_mid(const float* __restrict__ w_add, const float* __restrict__ p_la,
       const float* __restrict__ p_ea, float* __restrict__ ws) {
  __shared__ float hl[8192];  // gram: 2 x 16 KB halves; base: unused
  const int wave = threadIdx.x >> 6, lane = threadIdx.x & 63;
  const float* hp = ws + HP_OFF;
  float* z0 = ws + Z0_OFF;
  float* Wsc = ws + WS_OFF;

  if (blockIdx.x < 64) {
    // ---- gram: block (b, qq); wave halves handle q=qq / q=15-qq ----
    const int b = blockIdx.x & 7, qq = blockIdx.x >> 3;
    const int hlf = wave >> 2, w4 = wave & 3;
    const int q = hlf ? (15 - qq) : qq;
    float* hb = hl + hlf * 4096;
    const float lam = sigmoid_f(p_la[0]);
    const float eta = p_ea[0];
#pragma unroll
    for (int i = 0; i < 4; ++i)
      load_lds16(&hp[((q * 4 + w4) * 8 + b) * 1024 + i * 256 + 4 * lane],
                 &hb[w4 * 1024 + i * 256]);
    __syncthreads();
    v2f hv[4][8];  // constant-indexed
#pragma unroll
    for (int i = 0; i < 4; ++i)
#pragma unroll
      for (int j = 0; j < 8; ++j)
        hv[i][j] = ((const v2f*)hb)[i * 512 + lane + 64 * j];

    const float l2lam = __log2f(lam);
    const int tlim = q * 8 + 7;

#define LDG(p0, p1, p2, p3, p4, p5, p6, p7, tp)                                \
  do {                                                                         \
    const float* hr_ = hp + (((tp) >> 1) * 8 + b) * 1024 + ((tp) & 1);         \
    p0 = hr_[2 * lane];                                                        \
    p1 = hr_[2 * lane + 128];                                                  \
    p2 = hr_[2 * lane + 256];                                                  \
    p3 = hr_[2 * lane + 384];                                                  \
    p4 = hr_[2 * lane + 512];                                                  \
    p5 = hr_[2 * lane + 640];                                                  \
    p6 = hr_[2 * lane + 768];                                                  \
    p7 = hr_[2 * lane + 896];                                                  \
  } while (0)

#define CMPG(p0, p1, p2, p3, p4, p5, p6, p7, tp)                               \
  do {                                                                         \
    _Pragma("unroll") for (int i_ = 0; i_ < 4; ++i_) {                         \
      v2f a_ = hv[i_][0] * v2(p0);                                             \
      a_ = __builtin_elementwise_fma(hv[i_][1], v2(p1), a_);                   \
      a_ = __builtin_elementwise_fma(hv[i_][2], v2(p2), a_);                   \
      a_ = __builtin_elementwise_fma(hv[i_][3], v2(p3), a_);                   \
      a_ = __builtin_elementwise_fma(hv[i_][4], v2(p4), a_);                   \
      a_ = __builtin_elementwise_fma(hv[i_][5], v2(p5), a_);                   \
      a_ = __builtin_elementwise_fma(hv[i_][6], v2(p6), a_);                   \
      a_ = __builtin_elementwise_fma(hv[i_][7], v2(p7), a_);                   \
      a_ = dpp_red2(a_);                                                       \
      if (lane == 63) {                                                        \
        const int te_ = q * 8 + 2 * i_;                                        \
        if ((tp) < te_)                                                        \
          Wsc[(b * T_ + te_) * T_ + (tp)] =                                    \
              eta * exp2f(l2lam * (float)(te_ - 1 - (tp))) * a_.x;             \
        if ((tp) < te_ + 1)                                                    \
          Wsc[(b * T_ + te_ + 1) * T_ + (tp)] =                                \
              eta * exp2f(l2lam * (float)(te_ - (tp))) * a_.y;                 \
      }                                                                        \
    }                                                                          \
  } while (0)

    float ra0, ra1, ra2, ra3, ra4, ra5, ra6, ra7;
    float rb0, rb1, rb2, rb3, rb4, rb5, rb6, rb7;
    if (w4 < tlim) LDG(ra0, ra1, ra2, ra3, ra4, ra5, ra6, ra7, w4);
    for (int tp = w4; tp < tlim; tp += 4) {
      if (tp + 4 < tlim) LDG(rb0, rb1, rb2, rb3, rb4, rb5, rb6, rb7, tp + 4);
      CMPG(ra0, ra1, ra2, ra3, ra4, ra5, ra6, ra7, tp);
      ra0 = rb0; ra1 = rb1; ra2 = rb2; ra3 = rb3;
      ra4 = rb4; ra5 = rb5; ra6 = rb6; ra7 = rb7;
    }
#undef LDG
#undef CMPG
  } else {
    // ---- base: block (ng, pg): 64 n x 16 pr; named-register pipeline ----
    const int bx = blockIdx.x - 64;
    const int ng = bx >> 5, pg = bx & 31;
    const int l31 = lane & 31, half = lane >> 5;
    const int nb = ng * 64 + wave * 8 + half * 4;

    float4 wreg[4][4];  // constant-indexed
#pragma unroll
    for (int i = 0; i < 4; ++i) {
      const float* wr = w_add + (size_t)(nb + i) * N_ + 4 * l31;
#pragma unroll
      for (int jj = 0; jj < 4; ++jj)
        wreg[i][jj] = *(const float4*)&wr[128 * jj];
    }

    const float* hbase = hp + (size_t)pg * 16 * 1024 + 8 * l31;

#define LDH(h0, h1, h2, h3, h4, h5, h6, h7, it)                                \
  do {                                                                         \
    const float* hr_ = hbase + (size_t)(it) * 1024;                            \
    h0 = *(const float4*)&hr_[0];                                              \
    h1 = *(const float4*)&hr_[4];                                              \
    h2 = *(const float4*)&hr_[256];                                            \
    h3 = *(const float4*)&hr_[260];                                            \
    h4 = *(const float4*)&hr_[512];                                            \
    h5 = *(const float4*)&hr_[516];                                            \
    h6 = *(const float4*)&hr_[768];                                            \
    h7 = *(const float4*)&hr_[772];                                            \
  } while (0)

#define CMPB(h0, h1, h2, h3, h4, h5, h6, h7, it)                               \
  do {                                                                         \
    const int pr_ = pg * 16 + (it);                                            \
    const int rowe_ = 16 * (pr_ >> 3) + (pr_ & 7);                             \
    v2f a0_ = dot8p(wreg[0][0], wreg[0][1], wreg[0][2], wreg[0][3],            \
                    h0, h1, h2, h3, h4, h5, h6, h7);                           \
    v2f a1_ = dot8p(wreg[1][0], wreg[1][1], wreg[1][2], wreg[1][3],            \
                    h0, h1, h2, h3, h4, h5, h6, h7);                           \
    v2f a2_ = dot8p(wreg[2][0], wreg[2][1], wreg[2][2], wreg[2][3],            \
                    h0, h1, h2, h3, h4, h5, h6, h7);                           \
    v2f a3_ = dot8p(wreg[3][0], wreg[3][1], wreg[3][2], wreg[3][3],            \
                    h0, h1, h2, h3, h4, h5, h6, h7);                           \
    a0_ = dpp_red2_32(a0_);                                                    \
    a1_ = dpp_red2_32(a1_);                                                    \
    a2_ = dpp_red2_32(a2_);                                                    \
    a3_ = dpp_red2_32(a3_);                                                    \
    if (l31 == 31) {                                                           \
      *(float4*)&z0[rowe_ * N_ + nb] =                                         \
          make_float4(a0_.x, a1_.x, a2_.x, a3_.x);                             \
      *(float4*)&z0[(rowe_ + 8) * N_ + nb] =                                   \
          make_float4(a0_.y, a1_.y, a2_.y, a3_.y);                             \
    }                                                                          \
  } while (0)

    float4 A0, A1, A2, A3, A4, A5, A6, A7;
    float4 B0, B1, B2, B3, B4, B5, B6, B7;
    LDH(A0, A1, A2, A3, A4, A5, A6, A7, 0);
    for (int it = 0; it < 16; it += 2) {
      LDH(B0, B1, B2, B3, B4, B5, B6, B7, it + 1);
      CMPB(A0, A1, A2, A3, A4, A5, A6, A7, it);
      if (it + 2 < 16) LDH(A0, A1, A2, A3, A4, A5, A6, A7, it + 2);
      CMPB(B0, B1, B2, B3, B4, B5, B6, B7, it + 1);
    }
#undef LDH
#undef CMPB
  }
}

// ---------------- np_scan: right-looking sigmoid scan ----------------
// 64 blocks (b x 8 n-chunks of 64). Wave w owns rows {2w, 2w+1} of EVERY
// 16-tile: z[2][8] in registers. Per tile: publish z -> wave0 triangle ->
// scatter-forward this tile's u into all future tiles' z.
__global__ void __launch_bounds__(512, 1)
np_scan(const float* __restrict__ b_add, float* __restrict__ ws) {
  __shared__ float Wl[T_][T_];   // 64 KB
  __shared__ float ul[16][64];   // current tile's u (4 KB)
  __shared__ float zx[16][64];   // z exchange (4 KB)
  const int b = blockIdx.x >> 3, nc = blockIdx.x & 7;
  const int wave = threadIdx.x >> 6, lane = threadIdx.x & 63;
  float* z0 = ws + Z0_OFF;
  const float* Wb = ws + WS_OFF + b * T_ * T_;

#pragma unroll
  for (int i = 0; i < 8; ++i) {
    const int r2 = wave * 16 + i * 2;
    load_lds16(&Wb[r2 * T_ + 4 * lane], &Wl[r2][0]);
  }

  const int ta = 2 * wave, tb2 = 2 * wave + 1;
  const int ncol = nc * 64 + lane;
  const float ban = b_add[ncol];

  float za[8], zb[8];
#pragma unroll
  for (int j = 0; j < 8; ++j) {
    za[j] = z0[((j * 16 + ta) * B_ + b) * N_ + ncol] + ban;
    zb[j] = z0[((j * 16 + tb2) * B_ + b) * N_ + ncol] + ban;
  }
  __syncthreads();  // W staged

#pragma unroll
  for (int j = 0; j < 8; ++j) {
    const int t0 = j * 16;
    zx[ta][lane] = za[j];
    zx[tb2][lane] = zb[j];
    __syncthreads();
    if (wave == 0) {
      float z[16], uv[16];
#pragma unroll
      for (int i = 0; i < 16; ++i) z[i] = zx[i][lane];
#pragma unroll
      for (int i = 0; i < 16; ++i) {
        const float u = sigmoid_f(z[i]);
        uv[i] = u;
        z0[((t0 + i) * B_ + b) * N_ + ncol] = u;  // in-place u output
#pragma unroll
        for (int tt = i + 1; tt < 16; ++tt)
          z[tt] = __builtin_fmaf(u, Wl[t0 + tt][t0 + i], z[tt]);
      }
#pragma unroll
      for (int i = 0; i < 16; ++i) ul[i][lane] = uv[i];
    }
    __syncthreads();
    if (j < 7) {
      float u0[16];  // constant-indexed after unroll
#pragma unroll
      for (int i = 0; i < 16; ++i) u0[i] = ul[i][lane];
#pragma unroll
      for (int jf = j + 1; jf < 8; ++jf) {
        const int taf = jf * 16 + ta, tbf = jf * 16 + tb2;
        float sa0 = 0.f, sa1 = 0.f, sb0 = 0.f, sb1 = 0.f;
#pragma unroll
        for (int i = 0; i < 16; i += 4) {
          const float4 wa = *(const float4*)&Wl[taf][t0 + i];
          const float4 wb = *(const float4*)&Wl[tbf][t0 + i];
          sa0 = __builtin_fmaf(wa.x, u0[i], sa0);
          sa1 = __builtin_fmaf(wa.y, u0[i + 1], sa1);
          sa0 = __builtin_fmaf(wa.z, u0[i + 2], sa0);
          sa1 = __builtin_fmaf(wa.w, u0[i + 3], sa1);
          sb0 = __builtin_fmaf(wb.x, u0[i], sb0);
          sb1 = __builtin_fmaf(wb.y, u0[i + 1], sb1);
          sb0 = __builtin_fmaf(wb.z, u0[i + 2], sb0);
          sb1 = __builtin_fmaf(wb.w, u0[i + 3], sb1);
        }
        za[jf] += sa0 + sa1;
        zb[jf] += sb0 + sb1;
      }
    }
  }
}

// ---------------- np_final ----------------
__global__ void __launch_bounds__(512)
np_final(const float* __restrict__ ws, const float* __restrict__ w_final,
         const float* __restrict__ b_final, float* __restrict__ out) {
  const int wave = threadIdx.x >> 6, lane = threadIdx.x & 63;
  const int tb = blockIdx.x * 8 + wave;
  const float* u = ws + Z0_OFF + tb * N_ + lane * 8;
  const float4 a = *(const float4*)u, c = *(const float4*)(u + 4);
  const float4 wa = *(const float4*)&w_final[lane * 8];
  const float4 wc = *(const float4*)&w_final[lane * 8 + 4];
  float d = a.x * wa.x + a.y * wa.y + a.z * wa.z + a.w * wa.w +
            c.x * wc.x + c.y * wc.y + c.z * wc.z + c.w * wc.w;
  d = dpp_wave_sum(d);
  if (lane == 0) out[tb] = sigmoid_f(d + b_final[0]);
}

// ================= fallback path (R5) =================

__global__ void __launch_bounds__(512, 2)
fb_part1(const float* __restrict__ x, const float* __restrict__ w_mult,
         const float* __restrict__ b_mult, const float* __restrict__ p_lm,
         const float* __restrict__ p_em, float* __restrict__ ws) {
  const int g = blockIdx.x & 7, sub = blockIdx.x >> 3;
  const int wave = threadIdx.x >> 6, lane = threadIdx.x & 63;
  const int n0 = (sub * 8 + wave) * 2;
  __shared__ float xs[2][CH][D_];
  const float lam = sigmoid_f(p_lm[0]);
  const float eta = p_em[0];
  const v2f lam2 = v2(lam), klam2 = v2(1.f - lam);
  v2f wm[2][2], Bm[2][2];
  float bm[2];
#pragma unroll
  for (int r = 0; r < 2; ++r) {
    bm[r] = b_mult[n0 + r];
#pragma unroll
    for (int c = 0; c < 2; ++c) {
      wm[r][c] = *(const v2f*)&w_mult[(n0 + r) * D_ + c * 128 + 2 * lane];
      Bm[r][c] = v2(1.f);
    }
  }
  auto issue_stage = [&](int c) {
#pragma unroll
    for (int k = 0; k < 2; ++k) {
      const int row = k * 8 + wave;
      load_lds16(&x[((c * CH + row) * B_ + g) * D_ + 4 * lane],
                 &xs[c & 1][row][0]);
    }
  };
  issue_stage(0);
  __syncthreads();
  v2f xv[2][2];
  auto ldx = [&](int buf, int cb, int tl) {
    xv[buf][0] = *(const v2f*)&xs[cb][tl][2 * lane];
    xv[buf][1] = *(const v2f*)&xs[cb][tl][128 + 2 * lane];
  };
  for (int c = 0; c < NC; ++c) {
    if (c + 1 < NC) issue_stage(c + 1);
    const int cb = c & 1;
    ldx(0, cb, 0);
#pragma unroll
    for (int tl = 0; tl < CH; ++tl) {
      const int buf = tl & 1;
      if (tl + 1 < CH) ldx(buf ^ 1, cb, tl + 1);
      float hmv[2];
#pragma unroll
      for (int r = 0; r < 2; ++r) {
        v2f a = wm[r][0] * xv[buf][0] * Bm[r][0];
        a = __builtin_elementwise_fma(wm[r][1] * xv[buf][1], Bm[r][1], a);
        const float z = dpp_wave_sum(a.x + a.y) + bm[r];
        const float hm = tanh_f(z);
        hmv[r] = hm;
        const v2f c2 = v2(eta * hm);
#pragma unroll
        for (int cc = 0; cc < 2; ++cc) {
          v2f inner = __builtin_elementwise_fma(c2, xv[buf][cc], klam2);
          Bm[r][cc] = __builtin_elementwise_fma(lam2, Bm[r][cc], inner);
        }
      }
      if (lane == 0) {
        v2f hv2;
        hv2.x = hmv[0];
        hv2.y = hmv[1];
        *(v2f*)(ws + ((c * CH + tl) * B_ + g) * N_ + n0) = hv2;
      }
    }
    __syncthreads();
  }
}

__global__ void __launch_bounds__(512, 2)
fb_part2(const float* __restrict__ w_add, const float* __restrict__ b_add,
         const float* __restrict__ w_final, const float* __restrict__ p_la,
         const float* __restrict__ p_ea, float* __restrict__ ws) {
  const int g = blockIdx.x & 7, sub = blockIdx.x >> 3;
  const int wave = threadIdx.x >> 6, lane = threadIdx.x & 63;
  const int n0 = (sub * 8 + wave) * 2;
  __shared__ float hs[2][CH][N_];
  const float lam = sigmoid_f(p_la[0]);
  const float eta = p_ea[0];
  const v2f lam2 = v2(lam);
  const float klam = 1.f - lam;
  v2f Sa[2][4], wb[2][4];
  float ba[2], wf[2];
#pragma unroll
  for (int r = 0; r < 2; ++r) {
    ba[r] = b_add[n0 + r];
    wf[r] = w_final[n0 + r];
#pragma unroll
    for (int c = 0; c < 4; ++c) {
      const v2f wa = *(const v2f*)&w_add[(n0 + r) * N_ + c * 128 + 2 * lane];
      Sa[r][c] = wa;
      wb[r][c] = wa * klam;
    }
  }
  const float* hsrc = ws;
  float* part = ws + HOFF;
  auto issue_stage = [&](int c) {
#pragma unroll
    for (int k = 0; k < 2; ++k) {
      const int row = k * 8 + wave;
#pragma unroll
      for (int jj = 0; jj < 2; ++jj)
        load_lds16(&hsrc[((c * CH + row) * B_ + g) * N_ + jj * 256 + 4 * lane],
                   &hs[c & 1][row][jj * 256]);
    }
  };
  issue_stage(0);
  __syncthreads();
  v2f hv[2][4];
  auto ldh = [&](int buf, int cb, int tl) {
#pragma unroll
    for (int cc = 0; cc < 4; ++cc)
      hv[buf][cc] = *(const v2f*)&hs[cb][tl][cc * 128 + 2 * lane];
  };
  for (int c = 0; c < NC; ++c) {
    if (c + 1 < NC) issue_stage(c + 1);
    const int cb = c & 1;
    ldh(0, cb, 0);
#pragma unroll
    for (int tl = 0; tl < CH; ++tl) {
      const int buf = tl & 1;
      if (tl + 1 < CH) ldh(buf ^ 1, cb, tl + 1);
      float py = 0.f;
#pragma unroll
      for (int r = 0; r < 2; ++r) {
        v2f a0 = Sa[r][0] * hv[buf][0];
        v2f a1 = Sa[r][1] * hv[buf][1];
        a0 = __builtin_elementwise_fma(Sa[r][2], hv[buf][2], a0);
        a1 = __builtin_elementwise_fma(Sa[r][3], hv[buf][3], a1);
        const v2f a = a0 + a1;
        const float z = dpp_wave_sum(a.x + a.y) + ba[r];
        const float ha = sigmoid_f(z);
        const v2f c2 = v2(eta * ha);
#pragma unroll
        for (int cc = 0; cc < 4; ++cc) {
          v2f inner = __builtin_elementwise_fma(c2, hv[buf][cc], wb[r][cc]);
          Sa[r][cc] = __builtin_elementwise_fma(lam2, Sa[r][cc], inner);
        }
        py = __builtin_fmaf(wf[r], ha, py);
      }
      if (lane == 0)
        part[((c * CH + tl) * B_ + g) * 256 + sub * 8 + wave] = py;
    }
    __syncthreads();
  }
}

__global__ void __launch_bounds__(512)
fb_final(const float* __restrict__ ws, const float* __restrict__ b_final,
         float* __restrict__ out) {
  const int wave = threadIdx.x >> 6, lane = threadIdx.x & 63;
  const int tb = blockIdx.x * 8 + wave;
  const float4 v = *(const float4*)(ws + HOFF + tb * 256 + lane * 4);
  const float s = dpp_wave_sum((v.x + v.y) + (v.z + v.w));
  if (lane == 0) out[tb] = sigmoid_f(s + b_final[0]);
}

// ================= launch =================

extern "C" void kernel_launch(void* const* d_in, const int* in_sizes, int n_in,
                              void* d_out, int out_size, void* d_ws,
                              size_t ws_size, hipStream_t stream) {
  const float* x       = (const float*)d_in[0];
  const float* w_mult  = (const float*)d_in[1];
  const float* b_mult  = (const float*)d_in[2];
  const float* w_add   = (const float*)d_in[3];
  const float* b_add   = (const float*)d_in[4];
  const float* w_final = (const float*)d_in[5];
  const float* b_final = (const float*)d_in[6];
  const float* p_lm    = (const float*)d_in[7];
  const float* p_la    = (const float*)d_in[8];
  const float* p_em    = (const float*)d_in[9];
  const float* p_ea    = (const float*)d_in[10];
  float* out = (float*)d_out;
  float* ws  = (float*)d_ws;

  if (ws_size >= WS_NEED) {
    hipLaunchKernelGGL(np_part1, dim3(256), dim3(512), 0, stream,
                       x, w_mult, b_mult, p_lm, p_em, ws);
    hipLaunchKernelGGL(np_mid, dim3(320), dim3(512), 0, stream,
                       w_add, p_la, p_ea, ws);
    hipLaunchKernelGGL(np_scan, dim3(64), dim3(512), 0, stream, b_add, ws);
    hipLaunchKernelGGL(np_final, dim3(128), dim3(512), 0, stream,
                       ws, w_final, b_final, out);
  } else {
    hipLaunchKernelGGL(fb_part1, dim3(256), dim3(512), 0, stream,
                       x, w_mult, b_mult, p_lm, p_em, ws);
    hipLaunchKernelGGL(fb_part2, dim3(256), dim3(512), 0, stream,
                       w_add, b_add, w_final, p_la, p_ea, ws);
    hipLaunchKernelGGL(fb_final, dim3(128), dim3(512), 0, stream,
                       ws, b_final, out);
  }
}